// Round 1
// baseline (242.345 us; speedup 1.0000x reference)
//
#include <hip/hip_runtime.h>

#define ROWS 1024
#define COLS 1024
#define NN (ROWS*COLS)

static constexpr float RHOG      = 1000.0f * 9.81f;      // RHO_W * GRAV
static constexpr float INV_SEC   = 1.0f / 31556926.0f;   // 1 / SEC_PER_A
static constexpr float FLOWC     = 0.0405f;

// ---------------- phi = rho*g*bed + p ----------------
__global__ void k_phi(const float* __restrict__ bed, const float* __restrict__ pw,
                      float* __restrict__ phi) {
    int i = blockIdx.x * 256 + threadIdx.x;
    phi[i] = RHOG * bed[i] + pw[i];
}

// ---------------- inv_total[i] = core_i && total>0 ? 1/total : 0 ----------------
// total_i = sum over 4 neighbors of max(phi_i - phi_j, 0)
__global__ void k_inv(const float* __restrict__ phi, const int* __restrict__ status,
                      float* __restrict__ inv) {
    int i = blockIdx.x * 256 + threadIdx.x;
    int r = i >> 10, c = i & (COLS - 1);
    float p = phi[i];
    float t = 0.0f;
    if (c > 0)        t += fmaxf(p - phi[i - 1], 0.0f);
    if (c < COLS - 1) t += fmaxf(p - phi[i + 1], 0.0f);
    if (r > 0)        t += fmaxf(p - phi[i - COLS], 0.0f);
    if (r < ROWS - 1) t += fmaxf(p - phi[i + COLS], 0.0f);
    inv[i] = (status[i] == 0 && t > 0.0f) ? (1.0f / t) : 0.0f;
}

// ---------------- incoming weights per node (W,E,N,S) + runoff ----------------
// w_dir[i] = max(phi_j - phi_i, 0) * inv_total[j]   (j = neighbor in that dir)
__global__ void k_weights(const float* __restrict__ phi, const float* __restrict__ inv,
                          const float* __restrict__ melt, const float* __restrict__ area,
                          float4* __restrict__ w, float* __restrict__ runoff) {
    int i = blockIdx.x * 256 + threadIdx.x;
    int r = i >> 10, c = i & (COLS - 1);
    float p = phi[i];
    float4 wi = make_float4(0.f, 0.f, 0.f, 0.f);
    if (c > 0)        wi.x = fmaxf(phi[i - 1]    - p, 0.0f) * inv[i - 1];
    if (c < COLS - 1) wi.y = fmaxf(phi[i + 1]    - p, 0.0f) * inv[i + 1];
    if (r > 0)        wi.z = fmaxf(phi[i - COLS] - p, 0.0f) * inv[i - COLS];
    if (r < ROWS - 1) wi.w = fmaxf(phi[i + COLS] - p, 0.0f) * inv[i + COLS];
    w[i] = wi;
    runoff[i] = melt[i] * area[i] * INV_SEC;
}

// ---------------- one Jacobi step: qout = runoff + W.q_neighbors ----------------
__global__ void k_iter(const float4* __restrict__ w, const float* __restrict__ runoff,
                       const float* __restrict__ qin, float* __restrict__ qout) {
    int i = blockIdx.x * 256 + threadIdx.x;
    int r = i >> 10, c = i & (COLS - 1);
    float4 wi = w[i];
    // clamped indices: out-of-grid dirs have weight exactly 0, so any in-range
    // read is safe (0 * finite = 0)
    int iW = (c > 0)        ? i - 1    : i;
    int iE = (c < COLS - 1) ? i + 1    : i;
    int iN = (r > 0)        ? i - COLS : i;
    int iS = (r < ROWS - 1) ? i + COLS : i;
    float acc = runoff[i];
    acc = fmaf(wi.x, qin[iW], acc);
    acc = fmaf(wi.y, qin[iE], acc);
    acc = fmaf(wi.z, qin[iN], acc);
    acc = fmaf(wi.w, qin[iS], acc);
    qout[i] = acc;
}

// ---------------- epilogue: out = core ? (q*C*cond^1.25)^2 : 0 ----------------
__global__ void k_final(const float* __restrict__ q, const float* __restrict__ cond,
                        const int* __restrict__ status, float* __restrict__ out) {
    int i = blockIdx.x * 256 + threadIdx.x;
    float c = cond[i];
    float c125 = c * sqrtf(sqrtf(c));           // c^1.25, c > 0 always
    float g = q[i] * FLOWC * c125;
    out[i] = (status[i] == 0) ? g * g : 0.0f;
}

extern "C" void kernel_launch(void* const* d_in, const int* in_sizes, int n_in,
                              void* d_out, int out_size, void* d_ws, size_t ws_size,
                              hipStream_t stream) {
    const float* melt   = (const float*)d_in[0];
    const float* bed    = (const float*)d_in[1];
    const float* pw     = (const float*)d_in[2];
    const float* area   = (const float*)d_in[3];
    const float* cond   = (const float*)d_in[4];
    const int*   status = (const int*)d_in[5];
    // d_in[6], d_in[7] (link_src/link_dst) encode the fixed raster topology — derived analytically.
    float* out = (float*)d_out;

    char* ws = (char*)d_ws;
    float4* w      = (float4*)ws;                          // 16 MB
    float*  runoff = (float*)(ws + 16ull * NN);            //  4 MB
    float*  qA     = (float*)(ws + 20ull * NN);            //  4 MB
    float*  qB     = (float*)(ws + 24ull * NN);            //  4 MB  (total 28 MB)

    dim3 grid(NN / 256), block(256);
    // phi -> qA, inv_total -> qB (transient reuse before q ping-pong starts)
    k_phi<<<grid, block, 0, stream>>>(bed, pw, qA);
    k_inv<<<grid, block, 0, stream>>>(qA, status, qB);
    k_weights<<<grid, block, 0, stream>>>(qA, qB, melt, area, w, runoff);

    // q0 = runoff; 32 fixed-point steps, ping-pong qA/qB
    const float* qin = runoff;
    float* qout = qA;
    for (int it = 0; it < 32; ++it) {
        k_iter<<<grid, block, 0, stream>>>(w, runoff, qin, qout);
        qin = qout;
        qout = (qout == qA) ? qB : qA;
    }
    k_final<<<grid, block, 0, stream>>>(qin, cond, status, out);
}

// Round 2
// 185.656 us; speedup vs baseline: 1.3053x; 1.3053x over previous
//
#include <hip/hip_runtime.h>

#define ROWS 1024
#define COLS 1024
#define NN (ROWS*COLS)

#define TILE 32
#define HALO 8                 // steps fused per kernel
#define REG  48                // TILE + 2*HALO
#define RC   (REG*REG)         // 2304
#define NT   256
#define CPT  9                 // RC / NT == 9 exactly

static constexpr float RHOG    = 1000.0f * 9.81f;
static constexpr float INV_SEC = 1.0f / 31556926.0f;
static constexpr float FLOWC   = 0.0405f;

// ---- fused prologue: phi, inv_total, runoff in one pass --------------------
__global__ __launch_bounds__(256) void k_pre(
        const float* __restrict__ bed, const float* __restrict__ pw,
        const int* __restrict__ status,
        const float* __restrict__ melt, const float* __restrict__ area,
        float* __restrict__ phi, float* __restrict__ inv,
        float* __restrict__ runoff) {
    int i = blockIdx.x * 256 + threadIdx.x;
    int r = i >> 10, c = i & (COLS - 1);
    float p = RHOG * bed[i] + pw[i];
    float t = 0.0f;
    if (c > 0)        t += fmaxf(p - (RHOG * bed[i - 1]    + pw[i - 1]),    0.0f);
    if (c < COLS - 1) t += fmaxf(p - (RHOG * bed[i + 1]    + pw[i + 1]),    0.0f);
    if (r > 0)        t += fmaxf(p - (RHOG * bed[i - COLS] + pw[i - COLS]), 0.0f);
    if (r < ROWS - 1) t += fmaxf(p - (RHOG * bed[i + COLS] + pw[i + COLS]), 0.0f);
    phi[i]    = p;
    inv[i]    = (status[i] == 0 && t > 0.0f) ? (1.0f / t) : 0.0f;
    runoff[i] = melt[i] * area[i] * INV_SEC;
}

// ---- fused 8-step halo-tiled Jacobi ---------------------------------------
// Each block: 48x48 region around its 32x32 output tile. Weights recomputed
// once into registers from phi/inv (LDS), then 8 ping-pong steps entirely in
// LDS. Cell at region-border-distance d holds valid q^min(s,d) at step s;
// frozen cells forward-copy so the latest buffer is always fully valid.
template <bool FINAL>
__global__ __launch_bounds__(256) void k_fused(
        const float* __restrict__ phi_g, const float* __restrict__ inv_g,
        const float* __restrict__ runoff_g, const float* __restrict__ qin,
        float* __restrict__ qout,
        const float* __restrict__ cond, const int* __restrict__ status) {
    __shared__ float lds[2][RC];
    const int tid = threadIdx.x;
    const int r0 = (int)blockIdx.y * TILE - HALO;   // global row of local row 0
    const int c0 = (int)blockIdx.x * TILE - HALO;

    // phase 1: stage phi -> lds[0], inv -> lds[1] (OOG = 0)
#pragma unroll
    for (int k = 0; k < CPT; ++k) {
        int idx = tid + k * NT;
        int lr = idx / REG, lc = idx - lr * REG;
        int gr = r0 + lr, gc = c0 + lc;
        bool in = (gr >= 0) & (gr < ROWS) & (gc >= 0) & (gc < COLS);
        int g = gr * COLS + gc;
        lds[0][idx] = in ? phi_g[g] : 0.0f;
        lds[1][idx] = in ? inv_g[g] : 0.0f;
    }
    __syncthreads();

    // phase 2: per-owned-cell incoming weights (W,E,N,S), runoff, border dist
    float w0[CPT], w1[CPT], w2[CPT], w3[CPT], ro[CPT], oq[CPT];
    int dd[CPT];
#pragma unroll
    for (int k = 0; k < CPT; ++k) {
        int idx = tid + k * NT;
        int lr = idx / REG, lc = idx - lr * REG;
        float pi = lds[0][idx];
        int iW = (lc > 0)       ? idx - 1   : idx;
        int iE = (lc < REG - 1) ? idx + 1   : idx;
        int iN = (lr > 0)       ? idx - REG : idx;
        int iS = (lr < REG - 1) ? idx + REG : idx;
        w0[k] = fmaxf(lds[0][iW] - pi, 0.0f) * lds[1][iW];
        w1[k] = fmaxf(lds[0][iE] - pi, 0.0f) * lds[1][iE];
        w2[k] = fmaxf(lds[0][iN] - pi, 0.0f) * lds[1][iN];
        w3[k] = fmaxf(lds[0][iS] - pi, 0.0f) * lds[1][iS];
        dd[k] = min(min(lr, REG - 1 - lr), min(lc, REG - 1 - lc));
        int gr = r0 + lr, gc = c0 + lc;
        bool in = (gr >= 0) & (gr < ROWS) & (gc >= 0) & (gc < COLS);
        ro[k] = in ? runoff_g[gr * COLS + gc] : 0.0f;
    }
    __syncthreads();

    // phase 3: stage q^0 -> lds[0] (overwrites phi; weights already in regs)
#pragma unroll
    for (int k = 0; k < CPT; ++k) {
        int idx = tid + k * NT;
        int lr = idx / REG, lc = idx - lr * REG;
        int gr = r0 + lr, gc = c0 + lc;
        bool in = (gr >= 0) & (gr < ROWS) & (gc >= 0) & (gc < COLS);
        float v = in ? qin[gr * COLS + gc] : 0.0f;
        lds[0][idx] = v;
        oq[k] = v;
    }
    __syncthreads();

    // phase 4: 8 fused Jacobi steps, LDS ping-pong
    for (int s = 0; s < HALO; ++s) {
        const float* __restrict__ src = lds[s & 1];
        float* __restrict__ dst = lds[(s + 1) & 1];
#pragma unroll
        for (int k = 0; k < CPT; ++k) {
            int idx = tid + k * NT;
            if (s < dd[k]) {                     // updated cells are interior
                float acc = ro[k];
                acc = fmaf(w0[k], src[idx - 1],   acc);
                acc = fmaf(w1[k], src[idx + 1],   acc);
                acc = fmaf(w2[k], src[idx - REG], acc);
                acc = fmaf(w3[k], src[idx + REG], acc);
                oq[k] = acc;
            }
            dst[idx] = oq[k];                    // forward-copy keeps buffer valid
        }
        __syncthreads();
    }

    // phase 5: write the 32x32 output tile (q^8 lives in lds[HALO & 1])
    const float* __restrict__ fq = lds[HALO & 1];
#pragma unroll
    for (int k = 0; k < (TILE * TILE) / NT; ++k) {
        int idx = tid + k * NT;
        int lr = HALO + idx / TILE, lc = HALO + (idx & (TILE - 1));
        int gr = r0 + lr, gc = c0 + lc;          // always in-grid
        int g = gr * COLS + gc;
        float q = fq[lr * REG + lc];
        if (FINAL) {
            float c = cond[g];
            float c125 = c * sqrtf(sqrtf(c));    // c^1.25
            float gv = q * FLOWC * c125;
            qout[g] = (status[g] == 0) ? gv * gv : 0.0f;
        } else {
            qout[g] = q;
        }
    }
}

extern "C" void kernel_launch(void* const* d_in, const int* in_sizes, int n_in,
                              void* d_out, int out_size, void* d_ws, size_t ws_size,
                              hipStream_t stream) {
    const float* melt   = (const float*)d_in[0];
    const float* bed    = (const float*)d_in[1];
    const float* pw     = (const float*)d_in[2];
    const float* area   = (const float*)d_in[3];
    const float* cond   = (const float*)d_in[4];
    const int*   status = (const int*)d_in[5];
    // d_in[6]/d_in[7] (link_src/dst) encode the fixed raster topology — derived analytically.
    float* out = (float*)d_out;

    char* ws = (char*)d_ws;
    float* phi    = (float*)(ws);
    float* inv    = (float*)(ws + 4ull  * NN);
    float* runoff = (float*)(ws + 8ull  * NN);
    float* qA     = (float*)(ws + 12ull * NN);
    float* qB     = (float*)(ws + 16ull * NN);   // 20 MB total

    k_pre<<<dim3(NN / 256), dim3(256), 0, stream>>>(bed, pw, status, melt, area,
                                                    phi, inv, runoff);

    dim3 grid(COLS / TILE, ROWS / TILE), block(NT);
    // 32 iterations = 4 fused kernels x 8 steps; q^0 = runoff
    k_fused<false><<<grid, block, 0, stream>>>(phi, inv, runoff, runoff, qA, nullptr, nullptr);
    k_fused<false><<<grid, block, 0, stream>>>(phi, inv, runoff, qA, qB, nullptr, nullptr);
    k_fused<false><<<grid, block, 0, stream>>>(phi, inv, runoff, qB, qA, nullptr, nullptr);
    k_fused<true ><<<grid, block, 0, stream>>>(phi, inv, runoff, qA, out, cond, status);
}

// Round 3
// 155.807 us; speedup vs baseline: 1.5554x; 1.1916x over previous
//
#include <hip/hip_runtime.h>

#define ROWS 1024
#define COLS 1024
#define NN (ROWS*COLS)

#define TILE_H 32
#define TILE_W 64
#define HALO   8
#define RH     48              // TILE_H + 2*HALO
#define RW     80              // TILE_W + 2*HALO
#define RC     (RH*RW)         // 3840 cells
#define SPR    (RW/4)          // 20 strips per row
#define NSTRIP (RC/4)          // 960 strips
#define NT     320             // threads (5 waves)
#define SPT    3               // strips per thread

static constexpr float RHOG    = 1000.0f * 9.81f;
static constexpr float INV_SEC = 1.0f / 31556926.0f;
static constexpr float FLOWC   = 0.0405f;

// ---- fused prologue: phi, inv_total, runoff (validated in R1/R2) ----------
__global__ __launch_bounds__(256) void k_pre(
        const float* __restrict__ bed, const float* __restrict__ pw,
        const int* __restrict__ status,
        const float* __restrict__ melt, const float* __restrict__ area,
        float* __restrict__ phi, float* __restrict__ inv,
        float* __restrict__ runoff) {
    int i = blockIdx.x * 256 + threadIdx.x;
    int r = i >> 10, c = i & (COLS - 1);
    float p = RHOG * bed[i] + pw[i];
    float t = 0.0f;
    if (c > 0)        t += fmaxf(p - (RHOG * bed[i - 1]    + pw[i - 1]),    0.0f);
    if (c < COLS - 1) t += fmaxf(p - (RHOG * bed[i + 1]    + pw[i + 1]),    0.0f);
    if (r > 0)        t += fmaxf(p - (RHOG * bed[i - COLS] + pw[i - COLS]), 0.0f);
    if (r < ROWS - 1) t += fmaxf(p - (RHOG * bed[i + COLS] + pw[i + COLS]), 0.0f);
    phi[i]    = p;
    inv[i]    = (status[i] == 0 && t > 0.0f) ? (1.0f / t) : 0.0f;
    runoff[i] = melt[i] * area[i] * INV_SEC;
}

__device__ __forceinline__ float4 gld4(const float* __restrict__ p, int g, bool in) {
    if (in) return *reinterpret_cast<const float4*>(p + g);
    return make_float4(0.f, 0.f, 0.f, 0.f);
}

// ---- fused 8-step halo-tiled Jacobi, float4 strips + b128 LDS -------------
// Region 48x80 around a 32x64 tile. All LDS traffic in the step loop is
// ds_read_b128 / ds_write_b128 plus 2 scalar edge reads per strip.
// Cell at region-border-distance d holds q^min(s,d); clamped-index reads
// feed only dd=0 cells, which never update (cndmask keeps old value).
template <bool FIRST, bool FINAL>
__global__ __launch_bounds__(NT) void k_fused(
        const float* __restrict__ phi_g, const float* __restrict__ inv_g,
        const float* __restrict__ runoff_g, const float* __restrict__ qin,
        float* __restrict__ qout,
        const float* __restrict__ cond, const int* __restrict__ status) {
    __shared__ float lds[2][RC];
    const int tid = threadIdx.x;
    const int r0 = (int)blockIdx.y * TILE_H - HALO;
    const int c0 = (int)blockIdx.x * TILE_W - HALO;

    // per-strip geometry (word indices into the region, clamped)
    int xC[SPT], xW[SPT], xE[SPT], xN[SPT], xS[SPT], gg[SPT];
    int srA[SPT], scA[SPT];
    bool inA[SPT];
    float4 ro[SPT], q0[SPT];
    int4 dd[SPT];

#pragma unroll
    for (int j = 0; j < SPT; ++j) {
        int sid = tid + j * NT;
        int sr = sid / SPR, sc = sid - sr * SPR;
        srA[j] = sr; scA[j] = sc;
        int iC = sr * RW + 4 * sc;
        xC[j] = iC;
        xW[j] = (sc > 0)       ? iC - 1  : iC;
        xE[j] = (sc < SPR - 1) ? iC + 4  : iC;
        xN[j] = (sr > 0)       ? iC - RW : iC;
        xS[j] = (sr < RH - 1)  ? iC + RW : iC;
        int gr = r0 + sr, gc = c0 + 4 * sc;
        bool in = (gr >= 0) & (gr < ROWS) & (gc >= 0) & (gc < COLS);
        inA[j] = in;
        gg[j] = gr * COLS + gc;
        int drow = min(sr, RH - 1 - sr);
        int cc = 4 * sc;
        dd[j].x = min(drow, min(cc,     RW - 1 - cc));
        dd[j].y = min(drow, min(cc + 1, RW - 2 - cc));
        dd[j].z = min(drow, min(cc + 2, RW - 3 - cc));
        dd[j].w = min(drow, min(cc + 3, RW - 4 - cc));
    }

    // phase 1: stage phi->lds0, inv->lds1; runoff/qin straight to registers
    float4 pcA[SPT], icA[SPT];
#pragma unroll
    for (int j = 0; j < SPT; ++j) {
        float4 p4 = gld4(phi_g, gg[j], inA[j]);
        float4 i4 = gld4(inv_g, gg[j], inA[j]);
        ro[j] = gld4(runoff_g, gg[j], inA[j]);
        if (!FIRST) q0[j] = gld4(qin, gg[j], inA[j]);
        else        q0[j] = ro[j];
        pcA[j] = p4; icA[j] = i4;
        *reinterpret_cast<float4*>(&lds[0][xC[j]]) = p4;
        *reinterpret_cast<float4*>(&lds[1][xC[j]]) = i4;
    }
    __syncthreads();

    // phase 2: incoming weights (W,E,N,S) per cell into registers
    float4 w0[SPT], w1[SPT], w2[SPT], w3[SPT];
#pragma unroll
    for (int j = 0; j < SPT; ++j) {
        float4 pc = pcA[j], ic = icA[j];
        float pw_ = lds[0][xW[j]], pe_ = lds[0][xE[j]];
        float iw_ = lds[1][xW[j]], ie_ = lds[1][xE[j]];
        float4 pn = *reinterpret_cast<const float4*>(&lds[0][xN[j]]);
        float4 ps = *reinterpret_cast<const float4*>(&lds[0][xS[j]]);
        float4 vn = *reinterpret_cast<const float4*>(&lds[1][xN[j]]);
        float4 vs = *reinterpret_cast<const float4*>(&lds[1][xS[j]]);
        w0[j].x = fmaxf(pw_  - pc.x, 0.f) * iw_;
        w0[j].y = fmaxf(pc.x - pc.y, 0.f) * ic.x;
        w0[j].z = fmaxf(pc.y - pc.z, 0.f) * ic.y;
        w0[j].w = fmaxf(pc.z - pc.w, 0.f) * ic.z;
        w1[j].x = fmaxf(pc.y - pc.x, 0.f) * ic.y;
        w1[j].y = fmaxf(pc.z - pc.y, 0.f) * ic.z;
        w1[j].z = fmaxf(pc.w - pc.z, 0.f) * ic.w;
        w1[j].w = fmaxf(pe_  - pc.w, 0.f) * ie_;
        w2[j].x = fmaxf(pn.x - pc.x, 0.f) * vn.x;
        w2[j].y = fmaxf(pn.y - pc.y, 0.f) * vn.y;
        w2[j].z = fmaxf(pn.z - pc.z, 0.f) * vn.z;
        w2[j].w = fmaxf(pn.w - pc.w, 0.f) * vn.w;
        w3[j].x = fmaxf(ps.x - pc.x, 0.f) * vs.x;
        w3[j].y = fmaxf(ps.y - pc.y, 0.f) * vs.y;
        w3[j].z = fmaxf(ps.z - pc.z, 0.f) * vs.z;
        w3[j].w = fmaxf(ps.w - pc.w, 0.f) * vs.w;
    }
    __syncthreads();

    // phase 3: q^0 -> lds0
#pragma unroll
    for (int j = 0; j < SPT; ++j)
        *reinterpret_cast<float4*>(&lds[0][xC[j]]) = q0[j];
    __syncthreads();

    // phase 4: 8 Jacobi steps, LDS ping-pong, all-b128
    for (int s = 0; s < HALO; ++s) {
        const float* __restrict__ src = lds[s & 1];
        float* __restrict__ dst = lds[(s + 1) & 1];
#pragma unroll
        for (int j = 0; j < SPT; ++j) {
            float4 cv = *reinterpret_cast<const float4*>(&src[xC[j]]);
            float wv = src[xW[j]], ev = src[xE[j]];
            float4 nv = *reinterpret_cast<const float4*>(&src[xN[j]]);
            float4 sv = *reinterpret_cast<const float4*>(&src[xS[j]]);
            float4 acc;
            acc.x = fmaf(w0[j].x, wv,   ro[j].x);
            acc.y = fmaf(w0[j].y, cv.x, ro[j].y);
            acc.z = fmaf(w0[j].z, cv.y, ro[j].z);
            acc.w = fmaf(w0[j].w, cv.z, ro[j].w);
            acc.x = fmaf(w1[j].x, cv.y, acc.x);
            acc.y = fmaf(w1[j].y, cv.z, acc.y);
            acc.z = fmaf(w1[j].z, cv.w, acc.z);
            acc.w = fmaf(w1[j].w, ev,   acc.w);
            acc.x = fmaf(w2[j].x, nv.x, acc.x);
            acc.y = fmaf(w2[j].y, nv.y, acc.y);
            acc.z = fmaf(w2[j].z, nv.z, acc.z);
            acc.w = fmaf(w2[j].w, nv.w, acc.w);
            acc.x = fmaf(w3[j].x, sv.x, acc.x);
            acc.y = fmaf(w3[j].y, sv.y, acc.y);
            acc.z = fmaf(w3[j].z, sv.z, acc.z);
            acc.w = fmaf(w3[j].w, sv.w, acc.w);
            float4 out;
            out.x = (s < dd[j].x) ? acc.x : cv.x;
            out.y = (s < dd[j].y) ? acc.y : cv.y;
            out.z = (s < dd[j].z) ? acc.z : cv.z;
            out.w = (s < dd[j].w) ? acc.w : cv.w;
            *reinterpret_cast<float4*>(&dst[xC[j]]) = out;
        }
        __syncthreads();
    }

    // phase 5: write 32x64 tile (q^8 is in lds[0] after 8 steps)
#pragma unroll
    for (int j = 0; j < SPT; ++j) {
        int sr = srA[j], sc = scA[j];
        if (sr >= HALO && sr < RH - HALO && sc >= HALO / 4 && sc < SPR - HALO / 4) {
            float4 q = *reinterpret_cast<const float4*>(&lds[0][xC[j]]);
            int g = gg[j];
            if (FINAL) {
                float4 c4 = *reinterpret_cast<const float4*>(cond + g);
                int4 st   = *reinterpret_cast<const int4*>(status + g);
                float4 o;
                float t;
                t = q.x * FLOWC * (c4.x * sqrtf(sqrtf(c4.x))); o.x = (st.x == 0) ? t * t : 0.f;
                t = q.y * FLOWC * (c4.y * sqrtf(sqrtf(c4.y))); o.y = (st.y == 0) ? t * t : 0.f;
                t = q.z * FLOWC * (c4.z * sqrtf(sqrtf(c4.z))); o.z = (st.z == 0) ? t * t : 0.f;
                t = q.w * FLOWC * (c4.w * sqrtf(sqrtf(c4.w))); o.w = (st.w == 0) ? t * t : 0.f;
                *reinterpret_cast<float4*>(qout + g) = o;
            } else {
                *reinterpret_cast<float4*>(qout + g) = q;
            }
        }
    }
}

extern "C" void kernel_launch(void* const* d_in, const int* in_sizes, int n_in,
                              void* d_out, int out_size, void* d_ws, size_t ws_size,
                              hipStream_t stream) {
    const float* melt   = (const float*)d_in[0];
    const float* bed    = (const float*)d_in[1];
    const float* pw     = (const float*)d_in[2];
    const float* area   = (const float*)d_in[3];
    const float* cond   = (const float*)d_in[4];
    const int*   status = (const int*)d_in[5];
    float* out = (float*)d_out;

    char* ws = (char*)d_ws;
    float* phi    = (float*)(ws);
    float* inv    = (float*)(ws + 4ull  * NN);
    float* runoff = (float*)(ws + 8ull  * NN);
    float* qA     = (float*)(ws + 12ull * NN);
    float* qB     = (float*)(ws + 16ull * NN);   // 20 MB total

    k_pre<<<dim3(NN / 256), dim3(256), 0, stream>>>(bed, pw, status, melt, area,
                                                    phi, inv, runoff);

    dim3 grid(COLS / TILE_W, ROWS / TILE_H), block(NT);
    k_fused<true,  false><<<grid, block, 0, stream>>>(phi, inv, runoff, runoff, qA, nullptr, nullptr);
    k_fused<false, false><<<grid, block, 0, stream>>>(phi, inv, runoff, qA, qB, nullptr, nullptr);
    k_fused<false, false><<<grid, block, 0, stream>>>(phi, inv, runoff, qB, qA, nullptr, nullptr);
    k_fused<false, true ><<<grid, block, 0, stream>>>(phi, inv, runoff, qA, out, cond, status);
}